// Round 1
// baseline (113.888 us; speedup 1.0000x reference)
//
#include <hip/hip_runtime.h>
#include <math.h>

#define SMALL_EPS 1e-8f

// exp map: xi[6] -> R[3][3], t[3]
__device__ __forceinline__ void exp_se3(const float xi[6], float R[3][3], float t[3]) {
    const float x = xi[0], y = xi[1], z = xi[2];
    const float vx = xi[3], vy = xi[4], vz = xi[5];
    const float t2 = x * x + y * y + z * z;
    const float t2s = fmaxf(t2, 1e-12f);
    const float th = sqrtf(t2s);
    float s, c;
    __sincosf(th, &s, &c);
    const bool small = t2 < SMALL_EPS;
    const float A = small ? 1.0f - t2 * (1.0f / 6.0f) : s / th;
    const float B = small ? 0.5f - t2 * (1.0f / 24.0f) : (1.0f - c) / t2s;
    const float C = small ? (1.0f / 6.0f) - t2 * (1.0f / 120.0f) : (th - s) / (t2s * th);
    // W = hat(w); W^2 = w w^T - t2 * I
    R[0][0] = 1.0f + B * (x * x - t2);
    R[0][1] = -A * z + B * x * y;
    R[0][2] =  A * y + B * x * z;
    R[1][0] =  A * z + B * x * y;
    R[1][1] = 1.0f + B * (y * y - t2);
    R[1][2] = -A * x + B * y * z;
    R[2][0] = -A * y + B * x * z;
    R[2][1] =  A * x + B * y * z;
    R[2][2] = 1.0f + B * (z * z - t2);
    // V = I + B*W + C*W^2
    const float V00 = 1.0f + C * (x * x - t2);
    const float V01 = -B * z + C * x * y;
    const float V02 =  B * y + C * x * z;
    const float V10 =  B * z + C * x * y;
    const float V11 = 1.0f + C * (y * y - t2);
    const float V12 = -B * x + C * y * z;
    const float V20 = -B * y + C * x * z;
    const float V21 =  B * x + C * y * z;
    const float V22 = 1.0f + C * (z * z - t2);
    t[0] = V00 * vx + V01 * vy + V02 * vz;
    t[1] = V10 * vx + V11 * vy + V12 * vz;
    t[2] = V20 * vx + V21 * vy + V22 * vz;
}

// log map: (R, t) -> out[6], returns sum of squares of out via pointer
__device__ __forceinline__ float log_se3_sq(const float R[3][3], const float t[3]) {
    const float tr = R[0][0] + R[1][1] + R[2][2];
    const float cth = fminf(fmaxf((tr - 1.0f) * 0.5f, -1.0f), 1.0f);
    const float th = acosf(cth);
    const float t2 = th * th;
    const float t2s = fmaxf(t2, 1e-12f);
    const bool small = t2 < SMALL_EPS;
    const float sth = __sinf(th);
    const float fac = small ? 0.5f + t2 * (1.0f / 12.0f) : th / (2.0f * sth);
    const float wx = fac * (R[2][1] - R[1][2]);
    const float wy = fac * (R[0][2] - R[2][0]);
    const float wz = fac * (R[1][0] - R[0][1]);
    const float A = small ? 1.0f : sth / th;
    const float B = small ? 0.5f : (1.0f - cth) / t2s;
    const float coef = small ? (1.0f / 12.0f) + t2 * (1.0f / 720.0f)
                             : (1.0f - A / (2.0f * B)) / t2s;
    const float wa = wx * wx + wy * wy + wz * wz;
    // Vinv = I - 0.5*W + coef*(w w^T - wa I)
    const float V00 = 1.0f + coef * (wx * wx - wa);
    const float V01 =  0.5f * wz + coef * wx * wy;
    const float V02 = -0.5f * wy + coef * wx * wz;
    const float V10 = -0.5f * wz + coef * wx * wy;
    const float V11 = 1.0f + coef * (wy * wy - wa);
    const float V12 =  0.5f * wx + coef * wy * wz;
    const float V20 =  0.5f * wy + coef * wx * wz;
    const float V21 = -0.5f * wx + coef * wy * wz;
    const float V22 = 1.0f + coef * (wz * wz - wa);
    const float vx = V00 * t[0] + V01 * t[1] + V02 * t[2];
    const float vy = V10 * t[0] + V11 * t[1] + V12 * t[2];
    const float vz = V20 * t[0] + V21 * t[1] + V22 * t[2];
    return wx * wx + wy * wy + wz * wz + vx * vx + vy * vy + vz * vz;
}

__device__ __forceinline__ void load6(const float* __restrict__ p, float xi[6]) {
    // rows are 6 floats = 24 B, always 8-byte aligned
    const float2* p2 = reinterpret_cast<const float2*>(p);
    float2 a = p2[0], b = p2[1], c = p2[2];
    xi[0] = a.x; xi[1] = a.y; xi[2] = b.x; xi[3] = b.y; xi[4] = c.x; xi[5] = c.y;
}

__global__ void zero_out_kernel(float* out) { out[0] = 0.0f; }

__global__ __launch_bounds__(256) void pose_graph_loss_kernel(
    const float* __restrict__ poses,
    const int* __restrict__ edges,
    const float* __restrict__ meas,
    float* __restrict__ out,
    int N, int E, float invE)
{
    const int e = blockIdx.x * blockDim.x + threadIdx.x;
    float loss = 0.0f;
    if (e < E) {
        int i = edges[2 * e];
        int j = edges[2 * e + 1];
        // defensive clamp (indices are in [0,N) by construction)
        i = min(max(i, 0), N - 1);
        j = min(max(j, 0), N - 1);

        float xi_i[6], xi_j[6], xi_m[6];
        load6(poses + 6 * (size_t)i, xi_i);
        load6(poses + 6 * (size_t)j, xi_j);
        load6(meas + 6 * (size_t)e, xi_m);

        float Ri[3][3], ti[3], Rj[3][3], tj[3], Rm[3][3], tm[3];
        exp_se3(xi_i, Ri, ti);
        exp_se3(xi_j, Rj, tj);
        exp_se3(xi_m, Rm, tm);

        // Rc = Ri^T Rj ; tc = Ri^T (tj - ti)
        float d0 = tj[0] - ti[0], d1 = tj[1] - ti[1], d2 = tj[2] - ti[2];
        float Rc[3][3], tc[3];
        #pragma unroll
        for (int a = 0; a < 3; ++a) {
            #pragma unroll
            for (int b = 0; b < 3; ++b)
                Rc[a][b] = Ri[0][a] * Rj[0][b] + Ri[1][a] * Rj[1][b] + Ri[2][a] * Rj[2][b];
            tc[a] = Ri[0][a] * d0 + Ri[1][a] * d1 + Ri[2][a] * d2;
        }
        // Rr = Rm^T Rc ; tr = Rm^T (tc - tm)
        float e0 = tc[0] - tm[0], e1 = tc[1] - tm[1], e2 = tc[2] - tm[2];
        float Rr[3][3], tr[3];
        #pragma unroll
        for (int a = 0; a < 3; ++a) {
            #pragma unroll
            for (int b = 0; b < 3; ++b)
                Rr[a][b] = Rm[0][a] * Rc[0][b] + Rm[1][a] * Rc[1][b] + Rm[2][a] * Rc[2][b];
            tr[a] = Rm[0][a] * e0 + Rm[1][a] * e1 + Rm[2][a] * e2;
        }

        loss = log_se3_sq(Rr, tr);
    }

    // wave (64-lane) reduction
    #pragma unroll
    for (int off = 32; off > 0; off >>= 1)
        loss += __shfl_down(loss, off);

    __shared__ float sdata[4];
    const int lane = threadIdx.x & 63;
    const int wid = threadIdx.x >> 6;
    if (lane == 0) sdata[wid] = loss;
    __syncthreads();
    if (threadIdx.x == 0) {
        float s = (sdata[0] + sdata[1]) + (sdata[2] + sdata[3]);
        atomicAdd(out, s * invE);
    }
}

extern "C" void kernel_launch(void* const* d_in, const int* in_sizes, int n_in,
                              void* d_out, int out_size, void* d_ws, size_t ws_size,
                              hipStream_t stream) {
    const float* poses = (const float*)d_in[0];
    const int*   edges = (const int*)d_in[1];
    const float* meas  = (const float*)d_in[2];
    float* out = (float*)d_out;

    const int N = in_sizes[0] / 6;
    const int E = in_sizes[2] / 6;

    zero_out_kernel<<<1, 1, 0, stream>>>(out);

    const int block = 256;
    const int grid = (E + block - 1) / block;
    pose_graph_loss_kernel<<<grid, block, 0, stream>>>(
        poses, edges, meas, out, N, E, 1.0f / (float)E);
}

// Round 2
// 72.947 us; speedup vs baseline: 1.5612x; 1.5612x over previous
//
#include <hip/hip_runtime.h>
#include <math.h>

#define SMALL_EPS 1e-8f

__device__ __forceinline__ float frcp(float x) { return __builtin_amdgcn_rcpf(x); }
__device__ __forceinline__ float frsq(float x) { return __builtin_amdgcn_rsqf(x); }

// max abs err ~7e-5 rad (Abramowitz-Stegun 4.4.45)
__device__ __forceinline__ float fast_acos(float x) {
    float ax = fabsf(x);
    float r = sqrtf(fmaxf(1.0f - ax, 0.0f)) *
        (1.5707288f + ax * (-0.2121144f + ax * (0.0742610f + ax * (-0.0187293f))));
    return (x < 0.0f) ? (3.14159265358979f - r) : r;
}

// exp map: xi[6] -> R[3][3], t[3]  (fast-math version)
__device__ __forceinline__ void exp_se3(const float xi[6], float R[3][3], float t[3]) {
    const float x = xi[0], y = xi[1], z = xi[2];
    const float vx = xi[3], vy = xi[4], vz = xi[5];
    const float t2 = x * x + y * y + z * z;
    const float t2s = fmaxf(t2, 1e-12f);
    const float rt2 = frcp(t2s);     // 1/t2s
    const float rth = frsq(t2s);     // 1/sqrt(t2s)
    const float th  = t2s * rth;     // sqrt(t2s)
    float s, c;
    __sincosf(th, &s, &c);
    const bool small = t2 < SMALL_EPS;
    const float A = small ? 1.0f - t2 * (1.0f / 6.0f)          : s * rth;
    const float B = small ? 0.5f - t2 * (1.0f / 24.0f)         : (1.0f - c) * rt2;
    const float C = small ? (1.0f / 6.0f) - t2 * (1.0f / 120.0f) : (th - s) * rt2 * rth;
    // W = hat(w); W^2 = w w^T - t2 * I
    R[0][0] = 1.0f + B * (x * x - t2);
    R[0][1] = -A * z + B * x * y;
    R[0][2] =  A * y + B * x * z;
    R[1][0] =  A * z + B * x * y;
    R[1][1] = 1.0f + B * (y * y - t2);
    R[1][2] = -A * x + B * y * z;
    R[2][0] = -A * y + B * x * z;
    R[2][1] =  A * x + B * y * z;
    R[2][2] = 1.0f + B * (z * z - t2);
    // V = I + B*W + C*W^2
    const float V00 = 1.0f + C * (x * x - t2);
    const float V01 = -B * z + C * x * y;
    const float V02 =  B * y + C * x * z;
    const float V10 =  B * z + C * x * y;
    const float V11 = 1.0f + C * (y * y - t2);
    const float V12 = -B * x + C * y * z;
    const float V20 = -B * y + C * x * z;
    const float V21 =  B * x + C * y * z;
    const float V22 = 1.0f + C * (z * z - t2);
    t[0] = V00 * vx + V01 * vy + V02 * vz;
    t[1] = V10 * vx + V11 * vy + V12 * vz;
    t[2] = V20 * vx + V21 * vy + V22 * vz;
}

// log map: (R, t) -> sum of squares of xi  (fast-math version)
__device__ __forceinline__ float log_se3_sq(const float R[3][3], const float t[3]) {
    const float tr = R[0][0] + R[1][1] + R[2][2];
    const float cth = fminf(fmaxf((tr - 1.0f) * 0.5f, -1.0f), 1.0f);
    const float th = fast_acos(cth);
    const float t2 = th * th;
    const float t2s = fmaxf(t2, 1e-12f);
    const float rt2s = frcp(t2s);
    const bool small = t2 < SMALL_EPS;
    // sin(acos(x)) = sqrt(1-x^2), th in [0,pi] so sin >= 0
    const float sth = sqrtf(fmaxf(1.0f - cth * cth, 0.0f));
    const float fac = small ? 0.5f + t2 * (1.0f / 12.0f) : 0.5f * th * frcp(sth);
    const float wx = fac * (R[2][1] - R[1][2]);
    const float wy = fac * (R[0][2] - R[2][0]);
    const float wz = fac * (R[1][0] - R[0][1]);
    const float A = small ? 1.0f : sth * frcp(th);
    const float B = small ? 0.5f : (1.0f - cth) * rt2s;
    const float coef = small ? (1.0f / 12.0f) + t2 * (1.0f / 720.0f)
                             : (1.0f - 0.5f * A * frcp(B)) * rt2s;
    const float wa = wx * wx + wy * wy + wz * wz;
    // Vinv = I - 0.5*W + coef*(w w^T - wa I)
    const float V00 = 1.0f + coef * (wx * wx - wa);
    const float V01 =  0.5f * wz + coef * wx * wy;
    const float V02 = -0.5f * wy + coef * wx * wz;
    const float V10 = -0.5f * wz + coef * wx * wy;
    const float V11 = 1.0f + coef * (wy * wy - wa);
    const float V12 =  0.5f * wx + coef * wy * wz;
    const float V20 =  0.5f * wy + coef * wx * wz;
    const float V21 = -0.5f * wx + coef * wy * wz;
    const float V22 = 1.0f + coef * (wz * wz - wa);
    const float vx = V00 * t[0] + V01 * t[1] + V02 * t[2];
    const float vy = V10 * t[0] + V11 * t[1] + V12 * t[2];
    const float vz = V20 * t[0] + V21 * t[1] + V22 * t[2];
    return wa + vx * vx + vy * vy + vz * vz;
}

__device__ __forceinline__ void load6(const float* __restrict__ p, float xi[6]) {
    const float2* p2 = reinterpret_cast<const float2*>(p);
    float2 a = p2[0], b = p2[1], c = p2[2];
    xi[0] = a.x; xi[1] = a.y; xi[2] = b.x; xi[3] = b.y; xi[4] = c.x; xi[5] = c.y;
}

// ---------- kernel 1: exp all poses into 64B-padded records ----------
__global__ __launch_bounds__(256) void exp_poses_kernel(
    const float* __restrict__ poses, float* __restrict__ table, int N)
{
    const int i = blockIdx.x * blockDim.x + threadIdx.x;
    if (i >= N) return;
    float xi[6];
    load6(poses + 6 * (size_t)i, xi);
    float R[3][3], t[3];
    exp_se3(xi, R, t);
    float4* slot = reinterpret_cast<float4*>(table + 16 * (size_t)i);
    slot[0] = make_float4(R[0][0], R[0][1], R[0][2], R[1][0]);
    slot[1] = make_float4(R[1][1], R[1][2], R[2][0], R[2][1]);
    slot[2] = make_float4(R[2][2], t[0], t[1], t[2]);
}

__device__ __forceinline__ void load_pose(const float* __restrict__ table, int i,
                                          float R[3][3], float t[3])
{
    const float4* slot = reinterpret_cast<const float4*>(table + 16 * (size_t)i);
    float4 a = slot[0], b = slot[1], c = slot[2];
    R[0][0] = a.x; R[0][1] = a.y; R[0][2] = a.z; R[1][0] = a.w;
    R[1][1] = b.x; R[1][2] = b.y; R[2][0] = b.z; R[2][1] = b.w;
    R[2][2] = c.x; t[0] = c.y; t[1] = c.z; t[2] = c.w;
}

// ---------- kernel 2: per-edge residual, block partial sums ----------
__global__ __launch_bounds__(256) void edge_loss_kernel(
    const float* __restrict__ table,
    const int* __restrict__ edges,
    const float* __restrict__ meas,
    float* __restrict__ partials,
    int N, int E)
{
    const int e = blockIdx.x * blockDim.x + threadIdx.x;
    float loss = 0.0f;
    if (e < E) {
        int i = edges[2 * e];
        int j = edges[2 * e + 1];
        i = min(max(i, 0), N - 1);
        j = min(max(j, 0), N - 1);

        float Ri[3][3], ti[3], Rj[3][3], tj[3];
        load_pose(table, i, Ri, ti);
        load_pose(table, j, Rj, tj);

        float xi_m[6];
        load6(meas + 6 * (size_t)e, xi_m);
        float Rm[3][3], tm[3];
        exp_se3(xi_m, Rm, tm);

        // Rc = Ri^T Rj ; tc = Ri^T (tj - ti)
        const float d0 = tj[0] - ti[0], d1 = tj[1] - ti[1], d2 = tj[2] - ti[2];
        float Rc[3][3], tc[3];
        #pragma unroll
        for (int a = 0; a < 3; ++a) {
            #pragma unroll
            for (int b = 0; b < 3; ++b)
                Rc[a][b] = Ri[0][a] * Rj[0][b] + Ri[1][a] * Rj[1][b] + Ri[2][a] * Rj[2][b];
            tc[a] = Ri[0][a] * d0 + Ri[1][a] * d1 + Ri[2][a] * d2;
        }
        // Rr = Rm^T Rc ; tr = Rm^T (tc - tm)
        const float e0 = tc[0] - tm[0], e1 = tc[1] - tm[1], e2 = tc[2] - tm[2];
        float Rr[3][3], tr[3];
        #pragma unroll
        for (int a = 0; a < 3; ++a) {
            #pragma unroll
            for (int b = 0; b < 3; ++b)
                Rr[a][b] = Rm[0][a] * Rc[0][b] + Rm[1][a] * Rc[1][b] + Rm[2][a] * Rc[2][b];
            tr[a] = Rm[0][a] * e0 + Rm[1][a] * e1 + Rm[2][a] * e2;
        }
        loss = log_se3_sq(Rr, tr);
    }

    #pragma unroll
    for (int off = 32; off > 0; off >>= 1)
        loss += __shfl_down(loss, off);

    __shared__ float sdata[4];
    const int lane = threadIdx.x & 63;
    const int wid = threadIdx.x >> 6;
    if (lane == 0) sdata[wid] = loss;
    __syncthreads();
    if (threadIdx.x == 0)
        partials[blockIdx.x] = (sdata[0] + sdata[1]) + (sdata[2] + sdata[3]);
}

// ---------- kernel 3: final reduce ----------
__global__ __launch_bounds__(256) void reduce_kernel(
    const float* __restrict__ partials, int n, float* __restrict__ out, float invE)
{
    float s = 0.0f;
    for (int i = threadIdx.x; i < n; i += 256) s += partials[i];
    #pragma unroll
    for (int off = 32; off > 0; off >>= 1) s += __shfl_down(s, off);
    __shared__ float sd[4];
    const int lane = threadIdx.x & 63;
    const int wid = threadIdx.x >> 6;
    if (lane == 0) sd[wid] = s;
    __syncthreads();
    if (threadIdx.x == 0) out[0] = ((sd[0] + sd[1]) + (sd[2] + sd[3])) * invE;
}

// ---------- fallback (ws too small): fused, atomic ----------
__global__ void zero_out_kernel(float* out) { out[0] = 0.0f; }

__global__ __launch_bounds__(256) void fused_kernel(
    const float* __restrict__ poses,
    const int* __restrict__ edges,
    const float* __restrict__ meas,
    float* __restrict__ out,
    int N, int E, float invE)
{
    const int e = blockIdx.x * blockDim.x + threadIdx.x;
    float loss = 0.0f;
    if (e < E) {
        int i = edges[2 * e];
        int j = edges[2 * e + 1];
        i = min(max(i, 0), N - 1);
        j = min(max(j, 0), N - 1);
        float xi_i[6], xi_j[6], xi_m[6];
        load6(poses + 6 * (size_t)i, xi_i);
        load6(poses + 6 * (size_t)j, xi_j);
        load6(meas + 6 * (size_t)e, xi_m);
        float Ri[3][3], ti[3], Rj[3][3], tj[3], Rm[3][3], tm[3];
        exp_se3(xi_i, Ri, ti);
        exp_se3(xi_j, Rj, tj);
        exp_se3(xi_m, Rm, tm);
        const float d0 = tj[0] - ti[0], d1 = tj[1] - ti[1], d2 = tj[2] - ti[2];
        float Rc[3][3], tc[3];
        #pragma unroll
        for (int a = 0; a < 3; ++a) {
            #pragma unroll
            for (int b = 0; b < 3; ++b)
                Rc[a][b] = Ri[0][a] * Rj[0][b] + Ri[1][a] * Rj[1][b] + Ri[2][a] * Rj[2][b];
            tc[a] = Ri[0][a] * d0 + Ri[1][a] * d1 + Ri[2][a] * d2;
        }
        const float e0 = tc[0] - tm[0], e1 = tc[1] - tm[1], e2 = tc[2] - tm[2];
        float Rr[3][3], tr[3];
        #pragma unroll
        for (int a = 0; a < 3; ++a) {
            #pragma unroll
            for (int b = 0; b < 3; ++b)
                Rr[a][b] = Rm[0][a] * Rc[0][b] + Rm[1][a] * Rc[1][b] + Rm[2][a] * Rc[2][b];
            tr[a] = Rm[0][a] * e0 + Rm[1][a] * e1 + Rm[2][a] * e2;
        }
        loss = log_se3_sq(Rr, tr);
    }
    #pragma unroll
    for (int off = 32; off > 0; off >>= 1) loss += __shfl_down(loss, off);
    __shared__ float sdata[4];
    const int lane = threadIdx.x & 63;
    const int wid = threadIdx.x >> 6;
    if (lane == 0) sdata[wid] = loss;
    __syncthreads();
    if (threadIdx.x == 0)
        atomicAdd(out, ((sdata[0] + sdata[1]) + (sdata[2] + sdata[3])) * invE);
}

extern "C" void kernel_launch(void* const* d_in, const int* in_sizes, int n_in,
                              void* d_out, int out_size, void* d_ws, size_t ws_size,
                              hipStream_t stream) {
    const float* poses = (const float*)d_in[0];
    const int*   edges = (const int*)d_in[1];
    const float* meas  = (const float*)d_in[2];
    float* out = (float*)d_out;

    const int N = in_sizes[0] / 6;
    const int E = in_sizes[2] / 6;
    const float invE = 1.0f / (float)E;

    const int block = 256;
    const int grid_e = (E + block - 1) / block;
    const size_t table_bytes = (size_t)N * 16 * sizeof(float);      // 64 B / pose
    const size_t need = table_bytes + (size_t)grid_e * sizeof(float);

    if (ws_size >= need) {
        float* table = (float*)d_ws;
        float* partials = (float*)((char*)d_ws + table_bytes);
        const int grid_n = (N + block - 1) / block;
        exp_poses_kernel<<<grid_n, block, 0, stream>>>(poses, table, N);
        edge_loss_kernel<<<grid_e, block, 0, stream>>>(table, edges, meas, partials, N, E);
        reduce_kernel<<<1, block, 0, stream>>>(partials, grid_e, out, invE);
    } else {
        zero_out_kernel<<<1, 1, 0, stream>>>(out);
        fused_kernel<<<grid_e, block, 0, stream>>>(poses, edges, meas, out, N, E, invE);
    }
}